// Round 15
// baseline (987.111 us; speedup 1.0000x reference)
//
#include <hip/hip_runtime.h>
#include <math.h>

#define NEGS 0.2f
#define EPSF 1e-5f

typedef short s16x8 __attribute__((ext_vector_type(8)));
typedef float f32x4 __attribute__((ext_vector_type(4)));

__device__ __forceinline__ float b2f(unsigned short u) {
  union { unsigned int i; float f; } v; v.i = ((unsigned int)u) << 16; return v.f;
}
__device__ __forceinline__ unsigned short f2b(float f) {
  union { float f; unsigned int i; } v; v.f = f;
  unsigned int x = v.i;
  return (unsigned short)((x + 0x7fffu + ((x >> 16) & 1u)) >> 16);
}
__device__ __forceinline__ float eluf(float x) { return x > 0.f ? x : expm1f(x); }

__device__ __forceinline__ float bred256(float v, float* red) {
  #pragma unroll
  for (int o = 32; o > 0; o >>= 1) v += __shfl_down(v, o);
  __syncthreads();
  if ((threadIdx.x & 63) == 0) red[threadIdx.x >> 6] = v;
  __syncthreads();
  return red[0] + red[1] + red[2] + red[3];
}

// Manual grid barrier: all 1024 blocks co-resident by construction
// (LDS 22.5KB, VGPR<=128 via launch_bounds -> 4 blocks/CU x 256 CU = 1024).
__device__ __forceinline__ void gridbar(unsigned int* ctr) {
  __syncthreads();
  if (threadIdx.x == 0) {
    __threadfence();   // agent release: drain + L2 writeback (cross-XCD visibility)
    __hip_atomic_fetch_add(ctr, 1u, __ATOMIC_RELEASE, __HIP_MEMORY_SCOPE_AGENT);
    while (__hip_atomic_load(ctr, __ATOMIC_ACQUIRE, __HIP_MEMORY_SCOPE_AGENT) < 1024u)
      __builtin_amdgcn_s_sleep(8);
  }
  __syncthreads();
  __threadfence();     // acquire side: invalidate L1/L2 for all waves
}

__global__ __launch_bounds__(256, 4) void k_mega(
    const float* __restrict__ inp, const int* __restrict__ src,
    const float* __restrict__ W0, const float* __restrict__ al0, const float* __restrict__ ar0,
    const float* __restrict__ W1, const float* __restrict__ al1, const float* __restrict__ ar1,
    const float* __restrict__ W2, const float* __restrict__ al2, const float* __restrict__ ar2,
    const float* __restrict__ Wr2, const float* __restrict__ tc1w, const float* __restrict__ tc1b,
    const float* __restrict__ ln1g, const float* __restrict__ ln1b,
    const float* __restrict__ tc2w, const float* __restrict__ tc2b,
    const float* __restrict__ ln2g, const float* __restrict__ ln2b,
    const float* __restrict__ fcw, const float* __restrict__ fcb,
    float* __restrict__ out, unsigned int* __restrict__ bar,
    unsigned short* __restrict__ W1b, unsigned short* __restrict__ feat0,
    unsigned short* __restrict__ h1b, unsigned short* __restrict__ feat1,
    float* __restrict__ el0g, float* __restrict__ er0g,
    float* __restrict__ el1, float* __restrict__ er1,
    float* __restrict__ feat2, float* __restrict__ res2, float* __restrict__ x1v)
{
  __shared__ __align__(16) unsigned char U[22528];
  const int tid = threadIdx.x;
  const int bid = blockIdx.x;
  const int g   = bid & 7;                        // XCD-swizzle heuristic
  const int bt  = g*4 + ((bid >> 3) & 3);
  const int nBase = (bid >> 5) * 32;
  const int bb = bt >> 3, tt = bt & 7;
  const int w = tid >> 6, lane = tid & 63, n16 = lane & 15, q = lane >> 4;

  // ================= Phase A: feat0 = (inp^T) @ W0^T, fused el0/er0 =================
  {
    if (bid < 64) {   // W1 -> bf16 (consumed after barrier)
      const int j = bid * 256 + tid;
      float4 w4 = *(const float4*)&W1[j*4];
      ushort4 o4; o4.x=f2b(w4.x); o4.y=f2b(w4.y); o4.z=f2b(w4.z); o4.w=f2b(w4.w);
      *(ushort4*)&W1b[j*4] = o4;
    }
    unsigned short (*At)[72] = (unsigned short(*)[72])U;         // 4608 B
    unsigned short *Lb = (unsigned short*)(U + 4608);            // 16384 B
    s16x8 bw[2][4];
    #pragma unroll
    for (int kc = 0; kc < 2; ++kc)
      #pragma unroll
      for (int ct = 0; ct < 4; ++ct) {
        const float* p = &W0[(size_t)((w*4 + ct)*16 + n16)*64 + kc*32 + q*8];
        float4 wa = *(const float4*)p;
        float4 wbv = *(const float4*)(p + 4);
        s16x8 o;
        o[0]=(short)f2b(wa.x); o[1]=(short)f2b(wa.y); o[2]=(short)f2b(wa.z); o[3]=(short)f2b(wa.w);
        o[4]=(short)f2b(wbv.x); o[5]=(short)f2b(wbv.y); o[6]=(short)f2b(wbv.z); o[7]=(short)f2b(wbv.w);
        bw[kc][ct] = o;
      }
    {
      const int nn = tid & 31, cg2 = tid >> 5;
      #pragma unroll
      for (int c2 = 0; c2 < 4; ++c2) {
        int ch = cg2*8 + c2*2;
        float vx = inp[((size_t)(bb*64 + ch  )*8 + tt)*1024 + nBase + nn];
        float vy = inp[((size_t)(bb*64 + ch+1)*8 + tt)*1024 + nBase + nn];
        unsigned int pk = ((unsigned int)f2b(vy) << 16) | (unsigned int)f2b(vx);
        *(unsigned int*)&At[nn][ch] = pk;
      }
    }
    __syncthreads();
    f32x4 acc[2][4];
    #pragma unroll
    for (int rt = 0; rt < 2; ++rt)
      #pragma unroll
      for (int ct = 0; ct < 4; ++ct) acc[rt][ct] = (f32x4){0.f,0.f,0.f,0.f};
    #pragma unroll
    for (int kc = 0; kc < 2; ++kc) {
      s16x8 af[2];
      #pragma unroll
      for (int rt = 0; rt < 2; ++rt)
        af[rt] = *(const s16x8*)&At[rt*16 + n16][kc*32 + q*8];
      #pragma unroll
      for (int rt = 0; rt < 2; ++rt)
        #pragma unroll
        for (int ct = 0; ct < 4; ++ct)
          acc[rt][ct] = __builtin_amdgcn_mfma_f32_16x16x32_bf16(af[rt], bw[kc][ct], acc[rt][ct], 0, 0, 0);
    }
    float alv[4], arv[4];
    #pragma unroll
    for (int ct = 0; ct < 4; ++ct) {
      alv[ct] = al0[w*64 + ct*16 + n16];
      arv[ct] = ar0[w*64 + ct*16 + n16];
    }
    #pragma unroll
    for (int rt = 0; rt < 2; ++rt) {
      #pragma unroll
      for (int reg = 0; reg < 4; ++reg) {
        float pl = acc[rt][0][reg]*alv[0] + acc[rt][1][reg]*alv[1]
                 + acc[rt][2][reg]*alv[2] + acc[rt][3][reg]*alv[3];
        float pr = acc[rt][0][reg]*arv[0] + acc[rt][1][reg]*arv[1]
                 + acc[rt][2][reg]*arv[2] + acc[rt][3][reg]*arv[3];
        #pragma unroll
        for (int o = 1; o < 16; o <<= 1) { pl += __shfl_xor(pl, o); pr += __shfl_xor(pr, o); }
        if (n16 == 0) {
          int r = (nBase + rt*16 + q*4 + reg)*32 + bt;
          el0g[r*4 + w] = pl;
          er0g[r*4 + w] = pr;
        }
      }
    }
    #pragma unroll
    for (int rt = 0; rt < 2; ++rt)
      #pragma unroll
      for (int ct = 0; ct < 4; ++ct)
        #pragma unroll
        for (int reg = 0; reg < 4; ++reg)
          Lb[(rt*16 + q*4 + reg)*256 + w*64 + ct*16 + n16] = f2b(acc[rt][ct][reg]);
    __syncthreads();
    #pragma unroll
    for (int i = 0; i < 4; ++i) {
      int u = tid + i*256;
      int row = u >> 5, off = (u & 31) * 8;
      *(s16x8*)&feat0[(size_t)((nBase + row)*32 + bt)*256 + off] = *(const s16x8*)&Lb[row*256 + off];
    }
  }
  gridbar(&bar[0]);

  // ================= Phase B: h1 = elu(Agg(feat0)); feat1 = h1 @ W1^T; el1/er1 =====
  {
    int (*ssm)[8]      = (int(*)[8])U;                              // 1024 B
    float (*wsm)[8][4] = (float(*)[8][4])(U + 1024);                // 4096 B
    unsigned short (*Bt)[264] = (unsigned short(*)[264])(U + 5120); // 16896 B
    unsigned short *Lb2 = (unsigned short*)(U + 5120);
    ((int*)ssm)[tid] = src[nBase*8 + tid];
    __syncthreads();
    if (tid < 128) {
      const int nl = tid >> 2, h = tid & 3;
      const int rn = (nBase + nl)*32 + bt;
      const float erv = er0g[rn*4 + h];
      float e[8]; float mx = -1e30f;
      #pragma unroll
      for (int j = 0; j < 8; ++j) {
        float v = el0g[(ssm[nl][j]*32 + bt)*4 + h] + erv;
        v = v >= 0.f ? v : NEGS * v;
        e[j] = v; mx = fmaxf(mx, v);
      }
      float den = 0.f;
      #pragma unroll
      for (int j = 0; j < 8; ++j) { e[j] = __expf(e[j] - mx); den += e[j]; }
      const float inv = 1.f / den;
      #pragma unroll
      for (int j = 0; j < 8; ++j) wsm[nl][j][h] = e[j] * inv;
    }
    __syncthreads();
    {
      const int hw2 = tid >> 5, l5 = tid & 31;
      const int c0 = l5 * 8, hh = l5 >> 3;
      #pragma unroll
      for (int p2 = 0; p2 < 2; ++p2) {
        const int nlA = p2*16 + hw2, nlB = nlA + 8;
        s16x8 vA[8], vB[8];
        #pragma unroll
        for (int j = 0; j < 8; ++j) {
          vA[j] = *(const s16x8*)&feat0[(size_t)(ssm[nlA][j]*32 + bt)*256 + c0];
          vB[j] = *(const s16x8*)&feat0[(size_t)(ssm[nlB][j]*32 + bt)*256 + c0];
        }
        asm volatile("" ::: "memory");
        float aA[8] = {0,0,0,0,0,0,0,0}, aB[8] = {0,0,0,0,0,0,0,0};
        #pragma unroll
        for (int j = 0; j < 8; ++j) {
          const float wA = wsm[nlA][j][hh], wB = wsm[nlB][j][hh];
          #pragma unroll
          for (int i = 0; i < 8; ++i) {
            aA[i] = fmaf(wA, b2f((unsigned short)vA[j][i]), aA[i]);
            aB[i] = fmaf(wB, b2f((unsigned short)vB[j][i]), aB[i]);
          }
        }
        s16x8 oA, oB;
        #pragma unroll
        for (int i = 0; i < 8; ++i) {
          float xA = aA[i] > 0.f ? aA[i] : expm1f(aA[i]);
          float xB = aB[i] > 0.f ? aB[i] : expm1f(aB[i]);
          oA[i] = (short)f2b(xA); oB[i] = (short)f2b(xB);
        }
        *(s16x8*)&Bt[nlA][c0] = oA;
        *(s16x8*)&Bt[nlB][c0] = oB;
        *(s16x8*)&h1b[(size_t)((nBase + nlA)*32 + bt)*256 + c0] = oA;
        *(s16x8*)&h1b[(size_t)((nBase + nlB)*32 + bt)*256 + c0] = oB;
      }
    }
    __syncthreads();
    f32x4 acc[2][4];
    #pragma unroll
    for (int rt = 0; rt < 2; ++rt)
      #pragma unroll
      for (int ct = 0; ct < 4; ++ct) acc[rt][ct] = (f32x4){0.f,0.f,0.f,0.f};
    #pragma unroll
    for (int kc = 0; kc < 8; ++kc) {
      s16x8 af[2], bfr[4];
      #pragma unroll
      for (int rt = 0; rt < 2; ++rt)
        af[rt] = *(const s16x8*)&Bt[rt*16 + n16][kc*32 + q*8];
      #pragma unroll
      for (int ct = 0; ct < 4; ++ct)
        bfr[ct] = *(const s16x8*)&W1b[(size_t)((w*4 + ct)*16 + n16)*256 + kc*32 + q*8];
      #pragma unroll
      for (int rt = 0; rt < 2; ++rt)
        #pragma unroll
        for (int ct = 0; ct < 4; ++ct)
          acc[rt][ct] = __builtin_amdgcn_mfma_f32_16x16x32_bf16(af[rt], bfr[ct], acc[rt][ct], 0, 0, 0);
    }
    float alv[4], arv[4];
    #pragma unroll
    for (int ct = 0; ct < 4; ++ct) {
      alv[ct] = al1[w*64 + ct*16 + n16];
      arv[ct] = ar1[w*64 + ct*16 + n16];
    }
    #pragma unroll
    for (int rt = 0; rt < 2; ++rt) {
      #pragma unroll
      for (int reg = 0; reg < 4; ++reg) {
        float pl = acc[rt][0][reg]*alv[0] + acc[rt][1][reg]*alv[1]
                 + acc[rt][2][reg]*alv[2] + acc[rt][3][reg]*alv[3];
        float pr = acc[rt][0][reg]*arv[0] + acc[rt][1][reg]*arv[1]
                 + acc[rt][2][reg]*arv[2] + acc[rt][3][reg]*arv[3];
        #pragma unroll
        for (int o = 1; o < 16; o <<= 1) { pl += __shfl_xor(pl, o); pr += __shfl_xor(pr, o); }
        if (n16 == 0) {
          int r = (nBase + rt*16 + q*4 + reg)*32 + bt;
          el1[r*4 + w] = pl;
          er1[r*4 + w] = pr;
        }
      }
    }
    __syncthreads();
    #pragma unroll
    for (int rt = 0; rt < 2; ++rt)
      #pragma unroll
      for (int ct = 0; ct < 4; ++ct)
        #pragma unroll
        for (int reg = 0; reg < 4; ++reg)
          Lb2[(rt*16 + q*4 + reg)*256 + w*64 + ct*16 + n16] = f2b(acc[rt][ct][reg]);
    __syncthreads();
    #pragma unroll
    for (int i = 0; i < 4; ++i) {
      int u = tid + i*256;
      int row = u >> 5, off = (u & 31) * 8;
      *(s16x8*)&feat1[(size_t)((nBase + row)*32 + bt)*256 + off] = *(const s16x8*)&Lb2[row*256 + off];
    }
  }
  gridbar(&bar[1]);

  // ================= Phase C: h2 = elu(Agg(feat1)+h1); feat2/res2 = h2 @ [W2;Wres2]^T
  {
    int (*ssm)[8]      = (int(*)[8])U;
    float (*wsm)[8][4] = (float(*)[8][4])(U + 1024);
    float (*Wp)[256]   = (float(*)[256])(U + 5120);               // 8192 B
    ((int*)ssm)[tid] = src[nBase*8 + tid];
    for (int j2 = tid; j2 < 2048; j2 += 256) {
      int o = j2 >> 8, k = j2 & 255;
      Wp[o][k] = (o < 4) ? W2[o*256 + k] : Wr2[(o-4)*256 + k];
    }
    __syncthreads();
    if (tid < 128) {
      const int nl = tid >> 2, h = tid & 3;
      const int rn = (nBase + nl)*32 + bt;
      const float erv = er1[rn*4 + h];
      float e[8]; float mx = -1e30f;
      #pragma unroll
      for (int j = 0; j < 8; ++j) {
        float v = el1[(ssm[nl][j]*32 + bt)*4 + h] + erv;
        v = v >= 0.f ? v : NEGS * v;
        e[j] = v; mx = fmaxf(mx, v);
      }
      float den = 0.f;
      #pragma unroll
      for (int j = 0; j < 8; ++j) { e[j] = __expf(e[j] - mx); den += e[j]; }
      const float inv = 1.f / den;
      #pragma unroll
      for (int j = 0; j < 8; ++j) wsm[nl][j][h] = e[j] * inv;
    }
    __syncthreads();
    const int hw2 = tid >> 5, l5 = tid & 31;
    const int c0 = l5 * 8, hh = l5 >> 3;
    #pragma unroll
    for (int p2 = 0; p2 < 2; ++p2) {
      const int nlA = p2*16 + hw2, nlB = nlA + 8;
      const int rnA = (nBase + nlA)*32 + bt, rnB = (nBase + nlB)*32 + bt;
      s16x8 vA[8], vB[8], rrA, rrB;
      rrA = *(const s16x8*)&h1b[(size_t)rnA*256 + c0];
      rrB = *(const s16x8*)&h1b[(size_t)rnB*256 + c0];
      #pragma unroll
      for (int j = 0; j < 8; ++j) {
        vA[j] = *(const s16x8*)&feat1[(size_t)(ssm[nlA][j]*32 + bt)*256 + c0];
        vB[j] = *(const s16x8*)&feat1[(size_t)(ssm[nlB][j]*32 + bt)*256 + c0];
      }
      asm volatile("" ::: "memory");
      float aA[8] = {0,0,0,0,0,0,0,0}, aB[8] = {0,0,0,0,0,0,0,0};
      #pragma unroll
      for (int j = 0; j < 8; ++j) {
        const float wA = wsm[nlA][j][hh], wB = wsm[nlB][j][hh];
        #pragma unroll
        for (int i = 0; i < 8; ++i) {
          aA[i] = fmaf(wA, b2f((unsigned short)vA[j][i]), aA[i]);
          aB[i] = fmaf(wB, b2f((unsigned short)vB[j][i]), aB[i]);
        }
      }
      #pragma unroll
      for (int i = 0; i < 8; ++i) {
        float xA = aA[i] + b2f((unsigned short)rrA[i]);
        float xB = aB[i] + b2f((unsigned short)rrB[i]);
        aA[i] = xA > 0.f ? xA : expm1f(xA);
        aB[i] = xB > 0.f ? xB : expm1f(xB);
      }
      #pragma unroll
      for (int o = 0; o < 8; ++o) {
        float4 wa = *(const float4*)&Wp[o][c0];
        float4 wbv = *(const float4*)&Wp[o][c0 + 4];
        float pA = aA[0]*wa.x + aA[1]*wa.y + aA[2]*wa.z + aA[3]*wa.w
                 + aA[4]*wbv.x + aA[5]*wbv.y + aA[6]*wbv.z + aA[7]*wbv.w;
        float pB = aB[0]*wa.x + aB[1]*wa.y + aB[2]*wa.z + aB[3]*wa.w
                 + aB[4]*wbv.x + aB[5]*wbv.y + aB[6]*wbv.z + aB[7]*wbv.w;
        #pragma unroll
        for (int off = 1; off < 32; off <<= 1) {
          pA += __shfl_xor(pA, off);
          pB += __shfl_xor(pB, off);
        }
        if (l5 == 0) {
          if (o < 4) { feat2[rnA*4 + o] = pA; feat2[rnB*4 + o] = pB; }
          else       { res2[rnA*4 + (o-4)] = pA; res2[rnB*4 + (o-4)] = pB; }
        }
      }
    }
  }
  gridbar(&bar[2]);

  // ================= Phase D: layer-2 aggregate + tc1 einsum -> x1 =================
  {
    float (*os)[8][4] = (float(*)[8][4])U;   // [4][8][4]
    const int n = bid;
    if (tid < 128) {
      const int b2 = tid >> 5, t2 = (tid >> 2) & 7, h2 = tid & 3;
      const int rn = n*32 + b2*8 + t2;
      const float av = al2[h2], rv = ar2[h2];
      const float erv = feat2[rn*4 + h2] * rv;
      float f[8], e[8]; float m = -1e30f;
      #pragma unroll
      for (int j = 0; j < 8; ++j) {
        int s_ = src[n*8 + j];
        f[j] = feat2[(s_*32 + b2*8 + t2)*4 + h2];
        float v = f[j]*av + erv;
        v = v >= 0.f ? v : NEGS * v;
        e[j] = v; m = fmaxf(m, v);
      }
      float den = 0.f, num = 0.f;
      #pragma unroll
      for (int j = 0; j < 8; ++j) { float ex = __expf(e[j]-m); den += ex; num = fmaf(ex, f[j], num); }
      os[b2][t2][h2] = num/den + res2[rn*4 + h2];
    }
    __syncthreads();
    if (tid < 16) {
      int b2 = tid >> 2, o2 = tid & 3;
      float acc = tc1b[o2];
      #pragma unroll
      for (int hh = 0; hh < 4; ++hh)
        #pragma unroll
        for (int t3 = 0; t3 < 8; ++t3)
          acc = fmaf(tc1w[(o2*4 + hh)*8 + t3], os[b2][t3][hh], acc);
      x1v[(b2*4 + o2)*1024 + n] = acc;
    }
  }
  gridbar(&bar[3]);

  // ================= Phase E: LN1 -> tc2 -> LN2 -> conv -> out (blocks 0..3) =======
  if (bid < 4) {
    float* red = (float*)U;            // 16 B
    float* x2s = (float*)(U + 64);     // 4096 B
    const int b2 = bid;
    float s = 0.f, qq = 0.f;
    for (int j = tid; j < 4096; j += 256) {
      float v = x1v[b2*4096 + j];
      s += v; qq += v*v;
    }
    float S = bred256(s, red);
    float Q = bred256(qq, red);
    float mu  = S * (1.f/4096.f);
    float var = Q * (1.f/4096.f) - mu*mu;
    float inv = rsqrtf(var + EPSF);
    float tb = tc2b[0];
    float s2 = 0.f, q2 = 0.f;
    for (int nn = tid; nn < 1024; nn += 256) {
      float acc = tb;
      #pragma unroll
      for (int h = 0; h < 4; ++h) {
        float z = (x1v[b2*4096 + h*1024 + nn] - mu) * inv * ln1g[nn*4 + h] + ln1b[nn*4 + h];
        acc = fmaf(tc2w[h], z, acc);
      }
      x2s[nn] = acc;
      s2 += acc; q2 += acc*acc;
    }
    float S2 = bred256(s2, red);
    float Q2 = bred256(q2, red);
    float mu2  = S2 * (1.f/1024.f);
    float inv2 = rsqrtf(Q2 * (1.f/1024.f) - mu2*mu2 + EPSF);
    __syncthreads();
    for (int nn = tid; nn < 1024; nn += 256)
      x2s[nn] = (x2s[nn] - mu2) * inv2 * ln2g[nn] + ln2b[nn];
    __syncthreads();
    for (int c = 0; c < 7; ++c) {
      float p = 0.f;
      for (int k = tid; k < 1018; k += 256) p = fmaf(x2s[c + k], fcw[k], p);
      float P = bred256(p, red);
      if (tid == 0) out[b2*7 + c] = P + fcb[0];
    }
  }
}

extern "C" void kernel_launch(void* const* d_in, const int* in_sizes, int n_in,
                              void* d_out, int out_size, void* d_ws, size_t ws_size,
                              hipStream_t stream)
{
  const float* inp  = (const float*)d_in[0];
  const int*   src  = (const int*)  d_in[1];
  const float* W0   = (const float*)d_in[3];
  const float* al0  = (const float*)d_in[4];
  const float* ar0  = (const float*)d_in[5];
  const float* W1   = (const float*)d_in[6];
  const float* al1  = (const float*)d_in[7];
  const float* ar1  = (const float*)d_in[8];
  const float* W2   = (const float*)d_in[9];
  const float* al2  = (const float*)d_in[10];
  const float* ar2  = (const float*)d_in[11];
  const float* Wr2  = (const float*)d_in[12];
  const float* tc1w = (const float*)d_in[13];
  const float* tc1b = (const float*)d_in[14];
  const float* ln1g = (const float*)d_in[15];
  const float* ln1b = (const float*)d_in[16];
  const float* tc2w = (const float*)d_in[17];
  const float* tc2b = (const float*)d_in[18];
  const float* ln2g = (const float*)d_in[19];
  const float* ln2b = (const float*)d_in[20];
  const float* fcw  = (const float*)d_in[21];
  const float* fcb  = (const float*)d_in[22];
  float* out = (float*)d_out;

  unsigned int* bar = (unsigned int*)d_ws;                       // 4 counters (1 KB reserved)
  unsigned short* W1b    = (unsigned short*)((char*)d_ws + 1024); // 65,536
  unsigned short* feat0  = W1b   + 65536;                         // 8,388,608
  unsigned short* h1b    = feat0 + 8388608;                       // 8,388,608
  unsigned short* feat1  = h1b   + 8388608;                       // 8,388,608
  float* el0g  = (float*)(feat1 + 8388608);                       // 131,072
  float* er0g  = el0g  + 131072;
  float* el1   = er0g  + 131072;
  float* er1   = el1   + 131072;
  float* feat2 = er1   + 131072;
  float* res2  = feat2 + 131072;
  float* x1v   = res2  + 131072;                                  // 16,384

  hipMemsetAsync(d_ws, 0, 1024, stream);   // zero barrier counters (capturable)

  k_mega<<<dim3(1024), dim3(256), 0, stream>>>(
      inp, src, W0, al0, ar0, W1, al1, ar1, W2, al2, ar2, Wr2,
      tc1w, tc1b, ln1g, ln1b, tc2w, tc2b, ln2g, ln2b, fcw, fcb,
      out, bar, W1b, feat0, h1b, feat1, el0g, er0g, el1, er1,
      feat2, res2, x1v);
}

// Round 16
// 170.718 us; speedup vs baseline: 5.7821x; 5.7821x over previous
//
#include <hip/hip_runtime.h>
#include <math.h>

#define NEGS 0.2f
#define EPSF 1e-5f

typedef short s16x8 __attribute__((ext_vector_type(8)));
typedef float f32x4 __attribute__((ext_vector_type(4)));

__device__ __forceinline__ float b2f(unsigned short u) {
  union { unsigned int i; float f; } v; v.i = ((unsigned int)u) << 16; return v.f;
}
__device__ __forceinline__ unsigned short f2b(float f) {
  union { float f; unsigned int i; } v; v.f = f;
  unsigned int x = v.i;
  return (unsigned short)((x + 0x7fffu + ((x >> 16) & 1u)) >> 16);
}

__device__ __forceinline__ float block_reduce1024(float v, float* red) {
  #pragma unroll
  for (int o = 32; o > 0; o >>= 1) v += __shfl_down(v, o);
  __syncthreads();
  if ((threadIdx.x & 63) == 0) red[threadIdx.x >> 6] = v;
  __syncthreads();
  float s = 0.f;
  #pragma unroll
  for (int i = 0; i < 16; ++i) s += red[i];
  return s;
}

// ---- layer-0: feat0 = (inp^T) @ W0^T. XCD-swizzled: XCD g (blockIdx%8) owns bt in [4g,4g+4).
__global__ __launch_bounds__(256) void k_feat0(
    const float* __restrict__ inp, const float* __restrict__ W0,
    const float* __restrict__ W1, const float* __restrict__ al,
    const float* __restrict__ ar, unsigned short* __restrict__ feat,
    float* __restrict__ el, float* __restrict__ er,
    unsigned short* __restrict__ W1b)
{
  const int tid = threadIdx.x;
  if (blockIdx.x >= 512) {
    const int j = (blockIdx.x - 512) * 256 + tid;   // [0,16384)
    float4 w4 = *(const float4*)&W1[j*4];
    ushort4 o4; o4.x=f2b(w4.x); o4.y=f2b(w4.y); o4.z=f2b(w4.z); o4.w=f2b(w4.w);
    *(ushort4*)&W1b[j*4] = o4;
    return;
  }
  __shared__ __align__(16) unsigned short At[64][72];   // A-tile [node][ch]
  __shared__ __align__(16) unsigned short Lb[64*256];   // C bounce
  const int g  = blockIdx.x & 7;
  const int bt = g*4 + ((blockIdx.x >> 3) & 3);         // XCD-aligned bt slice
  const int n0 = (blockIdx.x >> 5) * 64;
  const int b  = bt >> 3, t = bt & 7;
  const int w    = tid >> 6;
  const int lane = tid & 63;
  const int n16  = lane & 15;
  const int q    = lane >> 4;
  s16x8 bf[2][4];   // W0 fragments in registers
  #pragma unroll
  for (int kc = 0; kc < 2; ++kc)
    #pragma unroll
    for (int ct = 0; ct < 4; ++ct) {
      const float* p = &W0[(size_t)((w*4 + ct)*16 + n16)*64 + kc*32 + q*8];
      float4 wa = *(const float4*)p;
      float4 wb = *(const float4*)(p + 4);
      s16x8 o;
      o[0]=(short)f2b(wa.x); o[1]=(short)f2b(wa.y); o[2]=(short)f2b(wa.z); o[3]=(short)f2b(wa.w);
      o[4]=(short)f2b(wb.x); o[5]=(short)f2b(wb.y); o[6]=(short)f2b(wb.z); o[7]=(short)f2b(wb.w);
      bf[kc][ct] = o;
    }
  {
    const int nn = tid & 63, cg = tid >> 6;
    #pragma unroll
    for (int c2 = 0; c2 < 8; ++c2) {
      int ch = (cg*8 + c2) * 2;
      float vx = inp[((size_t)(b*64 + ch  )*8 + t)*1024 + n0 + nn];
      float vy = inp[((size_t)(b*64 + ch+1)*8 + t)*1024 + n0 + nn];
      unsigned int pk = ((unsigned int)f2b(vy) << 16) | (unsigned int)f2b(vx);
      *(unsigned int*)&At[nn][ch] = pk;
    }
  }
  __syncthreads();
  f32x4 acc[4][4];
  #pragma unroll
  for (int rt = 0; rt < 4; ++rt)
    #pragma unroll
    for (int ct = 0; ct < 4; ++ct) acc[rt][ct] = (f32x4){0.f,0.f,0.f,0.f};
  #pragma unroll
  for (int kc = 0; kc < 2; ++kc) {
    s16x8 af[4];
    #pragma unroll
    for (int rt = 0; rt < 4; ++rt)
      af[rt] = *(const s16x8*)&At[rt*16 + n16][kc*32 + q*8];
    #pragma unroll
    for (int rt = 0; rt < 4; ++rt)
      #pragma unroll
      for (int ct = 0; ct < 4; ++ct)
        acc[rt][ct] = __builtin_amdgcn_mfma_f32_16x16x32_bf16(af[rt], bf[kc][ct], acc[rt][ct], 0, 0, 0);
  }
  float alv[4], arv[4];
  #pragma unroll
  for (int ct = 0; ct < 4; ++ct) {
    alv[ct] = al[w*64 + ct*16 + n16];
    arv[ct] = ar[w*64 + ct*16 + n16];
  }
  #pragma unroll
  for (int rt = 0; rt < 4; ++rt) {
    #pragma unroll
    for (int reg = 0; reg < 4; ++reg) {
      float pl = acc[rt][0][reg]*alv[0] + acc[rt][1][reg]*alv[1]
               + acc[rt][2][reg]*alv[2] + acc[rt][3][reg]*alv[3];
      float pr = acc[rt][0][reg]*arv[0] + acc[rt][1][reg]*arv[1]
               + acc[rt][2][reg]*arv[2] + acc[rt][3][reg]*arv[3];
      #pragma unroll
      for (int o = 1; o < 16; o <<= 1) { pl += __shfl_xor(pl, o); pr += __shfl_xor(pr, o); }
      if (n16 == 0) {
        int r = (n0 + rt*16 + q*4 + reg)*32 + bt;
        el[r*4 + w] = pl;
        er[r*4 + w] = pr;
      }
    }
  }
  #pragma unroll
  for (int rt = 0; rt < 4; ++rt)
    #pragma unroll
    for (int ct = 0; ct < 4; ++ct)
      #pragma unroll
      for (int reg = 0; reg < 4; ++reg)
        Lb[(rt*16 + q*4 + reg)*256 + w*64 + ct*16 + n16] = f2b(acc[rt][ct][reg]);
  __syncthreads();
  #pragma unroll
  for (int i = 0; i < 8; ++i) {
    int u = tid + i*256;
    int m = u >> 5, off = (u & 31) * 8;
    *(s16x8*)&feat[(size_t)((n0 + m)*32 + bt)*256 + off] = *(const s16x8*)&Lb[m*256 + off];
  }
}

// ------- agg0 + feat1, bt-sliced: block = (bt, 32-node chunk), same XCD swizzle. -------
__global__ __launch_bounds__(256, 4) void k_agg0_feat1(
    const unsigned short* __restrict__ feat0, const float* __restrict__ el0,
    const float* __restrict__ er0, const int* __restrict__ src,
    const unsigned short* __restrict__ W1b, const float* __restrict__ al,
    const float* __restrict__ ar, unsigned short* __restrict__ h1b,
    unsigned short* __restrict__ feat1, float* __restrict__ el1, float* __restrict__ er1)
{
  __shared__ float wsm[32][8][4];            // [node_local][j][h]
  __shared__ int   ssm[32][8];
  __shared__ __align__(16) unsigned short smbuf[32*264];  // A-tile (padded) / bounce
  unsigned short (*At)[264] = (unsigned short(*)[264])smbuf;
  unsigned short *Lb = smbuf;
  const int tid = threadIdx.x;
  const int g     = blockIdx.x & 7;
  const int bt    = g*4 + ((blockIdx.x >> 3) & 3);
  const int nBase = (blockIdx.x >> 5) * 32;
  ((int*)ssm)[tid] = src[nBase*8 + tid];
  __syncthreads();
  if (tid < 128) {
    const int nl = tid >> 2, h = tid & 3;
    const int rn = (nBase + nl)*32 + bt;
    const float erv = er0[rn*4 + h];
    float e[8]; float mx = -1e30f;
    #pragma unroll
    for (int j = 0; j < 8; ++j) {
      float v = el0[(ssm[nl][j]*32 + bt)*4 + h] + erv;
      v = v >= 0.f ? v : NEGS * v;
      e[j] = v; mx = fmaxf(mx, v);
    }
    float den = 0.f;
    #pragma unroll
    for (int j = 0; j < 8; ++j) { e[j] = __expf(e[j] - mx); den += e[j]; }
    const float inv = 1.f / den;
    #pragma unroll
    for (int j = 0; j < 8; ++j) wsm[nl][j][h] = e[j] * inv;
  }
  __syncthreads();
  // phase B: half-wave per node, 2 nodes per pass (16 loads in flight)
  {
    const int hw2 = tid >> 5, l5 = tid & 31;
    const int c0 = l5 * 8, hh = l5 >> 3;
    #pragma unroll
    for (int p2 = 0; p2 < 2; ++p2) {
      const int nlA = p2*16 + hw2, nlB = nlA + 8;
      s16x8 vA[8], vB[8];
      #pragma unroll
      for (int j = 0; j < 8; ++j) {
        vA[j] = *(const s16x8*)&feat0[(size_t)(ssm[nlA][j]*32 + bt)*256 + c0];
        vB[j] = *(const s16x8*)&feat0[(size_t)(ssm[nlB][j]*32 + bt)*256 + c0];
      }
      asm volatile("" ::: "memory");
      float aA[8] = {0,0,0,0,0,0,0,0}, aB[8] = {0,0,0,0,0,0,0,0};
      #pragma unroll
      for (int j = 0; j < 8; ++j) {
        const float wA = wsm[nlA][j][hh], wB = wsm[nlB][j][hh];
        #pragma unroll
        for (int i = 0; i < 8; ++i) {
          aA[i] = fmaf(wA, b2f((unsigned short)vA[j][i]), aA[i]);
          aB[i] = fmaf(wB, b2f((unsigned short)vB[j][i]), aB[i]);
        }
      }
      s16x8 oA, oB;
      #pragma unroll
      for (int i = 0; i < 8; ++i) {
        float xA = aA[i] > 0.f ? aA[i] : expm1f(aA[i]);
        float xB = aB[i] > 0.f ? aB[i] : expm1f(aB[i]);
        oA[i] = (short)f2b(xA); oB[i] = (short)f2b(xB);
      }
      *(s16x8*)&At[nlA][c0] = oA;
      *(s16x8*)&At[nlB][c0] = oB;
      *(s16x8*)&h1b[(size_t)((nBase + nlA)*32 + bt)*256 + c0] = oA;
      *(s16x8*)&h1b[(size_t)((nBase + nlB)*32 + bt)*256 + c0] = oB;
    }
  }
  __syncthreads();
  // phase C: MFMA 32x256 vs W1 (L2-resident). A-rows = 32 nodes at fixed bt.
  const int w    = tid >> 6;
  const int lane = tid & 63;
  const int n16  = lane & 15;
  const int q    = lane >> 4;
  f32x4 acc[2][4];
  #pragma unroll
  for (int rt = 0; rt < 2; ++rt)
    #pragma unroll
    for (int ct = 0; ct < 4; ++ct) acc[rt][ct] = (f32x4){0.f,0.f,0.f,0.f};
  #pragma unroll
  for (int kc = 0; kc < 8; ++kc) {
    s16x8 af[2], bfr[4];
    #pragma unroll
    for (int rt = 0; rt < 2; ++rt)
      af[rt] = *(const s16x8*)&At[rt*16 + n16][kc*32 + q*8];
    #pragma unroll
    for (int ct = 0; ct < 4; ++ct)
      bfr[ct] = *(const s16x8*)&W1b[(size_t)((w*4 + ct)*16 + n16)*256 + kc*32 + q*8];
    #pragma unroll
    for (int rt = 0; rt < 2; ++rt)
      #pragma unroll
      for (int ct = 0; ct < 4; ++ct)
        acc[rt][ct] = __builtin_amdgcn_mfma_f32_16x16x32_bf16(af[rt], bfr[ct], acc[rt][ct], 0, 0, 0);
  }
  float alv[4], arv[4];
  #pragma unroll
  for (int ct = 0; ct < 4; ++ct) {
    alv[ct] = al[w*64 + ct*16 + n16];
    arv[ct] = ar[w*64 + ct*16 + n16];
  }
  #pragma unroll
  for (int rt = 0; rt < 2; ++rt) {
    #pragma unroll
    for (int reg = 0; reg < 4; ++reg) {
      float pl = acc[rt][0][reg]*alv[0] + acc[rt][1][reg]*alv[1]
               + acc[rt][2][reg]*alv[2] + acc[rt][3][reg]*alv[3];
      float pr = acc[rt][0][reg]*arv[0] + acc[rt][1][reg]*arv[1]
               + acc[rt][2][reg]*arv[2] + acc[rt][3][reg]*arv[3];
      #pragma unroll
      for (int o = 1; o < 16; o <<= 1) { pl += __shfl_xor(pl, o); pr += __shfl_xor(pr, o); }
      if (n16 == 0) {
        int r = (nBase + rt*16 + q*4 + reg)*32 + bt;
        el1[r*4 + w] = pl;
        er1[r*4 + w] = pr;
      }
    }
  }
  __syncthreads();
  #pragma unroll
  for (int rt = 0; rt < 2; ++rt)
    #pragma unroll
    for (int ct = 0; ct < 4; ++ct)
      #pragma unroll
      for (int reg = 0; reg < 4; ++reg)
        Lb[(rt*16 + q*4 + reg)*256 + w*64 + ct*16 + n16] = f2b(acc[rt][ct][reg]);
  __syncthreads();
  #pragma unroll
  for (int i = 0; i < 4; ++i) {
    int u = tid + i*256;
    int row = u >> 5, off = (u & 31) * 8;
    *(s16x8*)&feat1[(size_t)((nBase + row)*32 + bt)*256 + off] = *(const s16x8*)&Lb[row*256 + off];
  }
}

// ------- agg1 + proj, bt-sliced: h2 = elu(Agg(feat1)+h1); feat2/res2 = h2 @ [W2;Wres2]^T -------
__global__ __launch_bounds__(256, 4) void k_agg1_proj(
    const unsigned short* __restrict__ feat1, const float* __restrict__ el,
    const float* __restrict__ er, const int* __restrict__ src,
    const unsigned short* __restrict__ h1b, const float* __restrict__ W2,
    const float* __restrict__ Wres2, float* __restrict__ feat2, float* __restrict__ res2)
{
  __shared__ float wsm[32][8][4];
  __shared__ int   ssm[32][8];
  __shared__ __align__(16) float Wp[8][256];
  const int tid = threadIdx.x;
  const int g     = blockIdx.x & 7;
  const int bt    = g*4 + ((blockIdx.x >> 3) & 3);
  const int nBase = (blockIdx.x >> 5) * 32;
  ((int*)ssm)[tid] = src[nBase*8 + tid];
  for (int j2 = tid; j2 < 2048; j2 += 256) {
    int o = j2 >> 8, k = j2 & 255;
    Wp[o][k] = (o < 4) ? W2[o*256 + k] : Wres2[(o-4)*256 + k];
  }
  __syncthreads();
  if (tid < 128) {
    const int nl = tid >> 2, h = tid & 3;
    const int rn = (nBase + nl)*32 + bt;
    const float erv = er[rn*4 + h];
    float e[8]; float mx = -1e30f;
    #pragma unroll
    for (int j = 0; j < 8; ++j) {
      float v = el[(ssm[nl][j]*32 + bt)*4 + h] + erv;
      v = v >= 0.f ? v : NEGS * v;
      e[j] = v; mx = fmaxf(mx, v);
    }
    float den = 0.f;
    #pragma unroll
    for (int j = 0; j < 8; ++j) { e[j] = __expf(e[j] - mx); den += e[j]; }
    const float inv = 1.f / den;
    #pragma unroll
    for (int j = 0; j < 8; ++j) wsm[nl][j][h] = e[j] * inv;
  }
  __syncthreads();
  const int hw2 = tid >> 5, l5 = tid & 31;
  const int c0 = l5 * 8, hh = l5 >> 3;
  #pragma unroll
  for (int p2 = 0; p2 < 2; ++p2) {
    const int nlA = p2*16 + hw2, nlB = nlA + 8;
    const int rnA = (nBase + nlA)*32 + bt, rnB = (nBase + nlB)*32 + bt;
    s16x8 vA[8], vB[8], rrA, rrB;
    rrA = *(const s16x8*)&h1b[(size_t)rnA*256 + c0];
    rrB = *(const s16x8*)&h1b[(size_t)rnB*256 + c0];
    #pragma unroll
    for (int j = 0; j < 8; ++j) {
      vA[j] = *(const s16x8*)&feat1[(size_t)(ssm[nlA][j]*32 + bt)*256 + c0];
      vB[j] = *(const s16x8*)&feat1[(size_t)(ssm[nlB][j]*32 + bt)*256 + c0];
    }
    asm volatile("" ::: "memory");
    float aA[8] = {0,0,0,0,0,0,0,0}, aB[8] = {0,0,0,0,0,0,0,0};
    #pragma unroll
    for (int j = 0; j < 8; ++j) {
      const float wA = wsm[nlA][j][hh], wB = wsm[nlB][j][hh];
      #pragma unroll
      for (int i = 0; i < 8; ++i) {
        aA[i] = fmaf(wA, b2f((unsigned short)vA[j][i]), aA[i]);
        aB[i] = fmaf(wB, b2f((unsigned short)vB[j][i]), aB[i]);
      }
    }
    #pragma unroll
    for (int i = 0; i < 8; ++i) {
      float xA = aA[i] + b2f((unsigned short)rrA[i]);
      float xB = aB[i] + b2f((unsigned short)rrB[i]);
      aA[i] = xA > 0.f ? xA : expm1f(xA);
      aB[i] = xB > 0.f ? xB : expm1f(xB);
    }
    #pragma unroll
    for (int o = 0; o < 8; ++o) {
      float4 wa = *(const float4*)&Wp[o][c0];
      float4 wb = *(const float4*)&Wp[o][c0 + 4];
      float pA = aA[0]*wa.x + aA[1]*wa.y + aA[2]*wa.z + aA[3]*wa.w
               + aA[4]*wb.x + aA[5]*wb.y + aA[6]*wb.z + aA[7]*wb.w;
      float pB = aB[0]*wa.x + aB[1]*wa.y + aB[2]*wa.z + aB[3]*wa.w
               + aB[4]*wb.x + aB[5]*wb.y + aB[6]*wb.z + aB[7]*wb.w;
      #pragma unroll
      for (int off = 1; off < 32; off <<= 1) {
        pA += __shfl_xor(pA, off);
        pB += __shfl_xor(pB, off);
      }
      if (l5 == 0) {
        if (o < 4) { feat2[rnA*4 + o] = pA; feat2[rnB*4 + o] = pB; }
        else       { res2[rnA*4 + (o-4)] = pA; res2[rnB*4 + (o-4)] = pB; }
      }
    }
  }
}

// ---------------- layer 2 aggregate + tc1 einsum -> x1[b][o][n] ----------------
__global__ __launch_bounds__(128) void k_agg2(
    const float* __restrict__ feat2, const float* __restrict__ res2,
    const int* __restrict__ src, const float* __restrict__ al2,
    const float* __restrict__ ar2, const float* __restrict__ tc1w,
    const float* __restrict__ tc1b, float* __restrict__ x1)
{
  __shared__ float os[4][8][4];   // [b][t][h]
  const int n = blockIdx.x;
  const int tid = threadIdx.x;
  const int b = tid >> 5, t = (tid >> 2) & 7, h = tid & 3;
  const int rn = n*32 + b*8 + t;
  const float av = al2[h], rv = ar2[h];
  const float erv = feat2[rn*4 + h] * rv;
  float f[8], e[8]; float m = -1e30f;
  #pragma unroll
  for (int j = 0; j < 8; ++j) {
    int s_ = src[n*8 + j];
    f[j] = feat2[(s_*32 + b*8 + t)*4 + h];
    float v = f[j]*av + erv;
    v = v >= 0.f ? v : NEGS * v;
    e[j] = v; m = fmaxf(m, v);
  }
  float den = 0.f, num = 0.f;
  #pragma unroll
  for (int j = 0; j < 8; ++j) { float ex = __expf(e[j]-m); den += ex; num = fmaf(ex, f[j], num); }
  os[b][t][h] = num/den + res2[rn*4 + h];
  __syncthreads();
  if (tid < 16) {
    int b2 = tid >> 2, o2 = tid & 3;
    float acc = tc1b[o2];
    #pragma unroll
    for (int hh = 0; hh < 4; ++hh)
      #pragma unroll
      for (int tt = 0; tt < 8; ++tt)
        acc = fmaf(tc1w[(o2*4 + hh)*8 + tt], os[b2][tt][hh], acc);
    x1[(b2*4 + o2)*1024 + n] = acc;
  }
}

// ---------------- head: LN1 -> tc2 -> LN2 -> conv -> out (B x 7) ----------------
__global__ __launch_bounds__(1024) void k_final(
    const float* __restrict__ x1, const float* __restrict__ ln1g,
    const float* __restrict__ ln1b, const float* __restrict__ tc2w,
    const float* __restrict__ tc2b, const float* __restrict__ ln2g,
    const float* __restrict__ ln2b, const float* __restrict__ fcw,
    const float* __restrict__ fcb, float* __restrict__ out)
{
  __shared__ float red[16];
  __shared__ float x2s[1024];
  const int b = blockIdx.x;
  const int tid = threadIdx.x;
  float s = 0.f, q = 0.f;
  for (int j = tid; j < 4096; j += 1024) {
    float v = x1[b*4096 + j];
    s += v; q += v*v;
  }
  float S = block_reduce1024(s, red);
  float Q = block_reduce1024(q, red);
  float mu  = S * (1.f/4096.f);
  float var = Q * (1.f/4096.f) - mu*mu;
  float inv = rsqrtf(var + EPSF);
  float tb = tc2b[0];
  const int nn = tid;
  float acc = tb;
  #pragma unroll
  for (int h = 0; h < 4; ++h) {
    float z = (x1[b*4096 + h*1024 + nn] - mu) * inv * ln1g[nn*4 + h] + ln1b[nn*4 + h];
    acc = fmaf(tc2w[h], z, acc);
  }
  float S2 = block_reduce1024(acc, red);
  float Q2 = block_reduce1024(acc*acc, red);
  float mu2  = S2 * (1.f/1024.f);
  float inv2 = rsqrtf(Q2 * (1.f/1024.f) - mu2*mu2 + EPSF);
  x2s[nn] = (acc - mu2) * inv2 * ln2g[nn] + ln2b[nn];
  __syncthreads();
  for (int c = 0; c < 7; ++c) {
    float p = (tid < 1018) ? x2s[c + tid] * fcw[tid] : 0.f;
    float P = block_reduce1024(p, red);
    if (tid == 0) out[b*7 + c] = P + fcb[0];
  }
}

extern "C" void kernel_launch(void* const* d_in, const int* in_sizes, int n_in,
                              void* d_out, int out_size, void* d_ws, size_t ws_size,
                              hipStream_t stream)
{
  const float* inp  = (const float*)d_in[0];
  const int*   src  = (const int*)  d_in[1];
  const float* W0   = (const float*)d_in[3];
  const float* al0  = (const float*)d_in[4];
  const float* ar0  = (const float*)d_in[5];
  const float* W1   = (const float*)d_in[6];
  const float* al1  = (const float*)d_in[7];
  const float* ar1  = (const float*)d_in[8];
  const float* W2   = (const float*)d_in[9];
  const float* al2  = (const float*)d_in[10];
  const float* ar2  = (const float*)d_in[11];
  const float* Wr2  = (const float*)d_in[12];
  const float* tc1w = (const float*)d_in[13];
  const float* tc1b = (const float*)d_in[14];
  const float* ln1g = (const float*)d_in[15];
  const float* ln1b = (const float*)d_in[16];
  const float* tc2w = (const float*)d_in[17];
  const float* tc2b = (const float*)d_in[18];
  const float* ln2g = (const float*)d_in[19];
  const float* ln2b = (const float*)d_in[20];
  const float* fcw  = (const float*)d_in[21];
  const float* fcb  = (const float*)d_in[22];
  float* out = (float*)d_out;

  unsigned short* W1b    = (unsigned short*)d_ws;    // 65,536
  unsigned short* featb0 = W1b    + 65536;           // 8,388,608
  unsigned short* featb1 = featb0 + 8388608;         // 8,388,608
  unsigned short* h1b    = featb1 + 8388608;         // 8,388,608
  float* el0   = (float*)(h1b + 8388608);            // 131,072
  float* er0   = el0   + 131072;
  float* el1   = er0   + 131072;
  float* er1   = el1   + 131072;
  float* feat2 = er1   + 131072;
  float* res2  = feat2 + 131072;
  float* x1    = res2  + 131072;                     // 16,384

  k_feat0<<<dim3(576), dim3(256), 0, stream>>>(inp, W0, W1, al0, ar0,
                                               featb0, el0, er0, W1b);
  k_agg0_feat1<<<dim3(1024), dim3(256), 0, stream>>>(featb0, el0, er0, src, W1b, al1, ar1,
                                                     h1b, featb1, el1, er1);
  k_agg1_proj<<<dim3(1024), dim3(256), 0, stream>>>(featb1, el1, er1, src, h1b, W2, Wr2,
                                                    feat2, res2);
  k_agg2<<<dim3(1024), dim3(128), 0, stream>>>(feat2, res2, src, al2, ar2, tc1w, tc1b, x1);
  k_final<<<dim3(4), dim3(1024), 0, stream>>>(x1, ln1g, ln1b, tc2w, tc2b, ln2g, ln2b, fcw, fcb, out);
}